// Round 7
// baseline (651.309 us; speedup 1.0000x reference)
//
#include <hip/hip_runtime.h>

#define DD 128
#define RNUM 20

typedef __attribute__((ext_vector_type(4))) float f32x4;
typedef __attribute__((ext_vector_type(8))) short s16x8;
typedef unsigned long long u64;
typedef unsigned int u32;

__device__ inline ushort f2bf(float f) {
    unsigned u = __float_as_uint(f);
    unsigned r = (u + 0x7FFF + ((u >> 16) & 1)) >> 16;  // RNE
    return (ushort)r;
}

// meta layout (u32): [0..19] rcnt; [20..40] rbase; [41..61] rtileoff; u64 totals @ 88
#define M_RCNT 0
#define M_RBASE 20
#define M_RTILE 41
#define M_TOT 88
#define BRSTRIDE 2048

// ---------------- weight prep / embedding gather ----------------

__global__ void k_transpose(const float* w1, const float* root1,
                            const float* w2, const float* root2,
                            ushort* wt1, ushort* wt2) {
    int m = blockIdx.x;  // 0..41
    const float* src;
    ushort* dst;
    if (m < 21) { src = (m == 20) ? root1 : w1 + m * DD * DD; dst = wt1 + m * DD * DD; }
    else { int mm = m - 21; src = (mm == 20) ? root2 : w2 + mm * DD * DD; dst = wt2 + mm * DD * DD; }
    for (int idx = threadIdx.x; idx < DD * DD; idx += blockDim.x) {
        int n = idx >> 7, k = idx & 127;
        dst[idx] = f2bf(src[k * DD + n]);   // wt[n][k] = w[k][n]
    }
}

__global__ void k_gather_h(const int* x, const float* emb, ushort* h, int N) {
    int id = blockIdx.x * blockDim.x + threadIdx.x;  // one thread per 4 elems
    if (id >= N * 32) return;
    int n = id >> 5, c = (id & 31) * 4;
    int xn = x[n];
    float4 v = *(const float4*)(emb + (size_t)xn * DD + c);
    ushort4 o;
    o.x = f2bf(v.x); o.y = f2bf(v.y); o.z = f2bf(v.z); o.w = f2bf(v.w);
    *(ushort4*)(h + (size_t)n * DD + c) = o;
}

// ---------------- sort-by-(dst,rel) preprocessing ----------------

__global__ void k_hist(const int* edge, const int* et, int E, u32* cnt) {
    int e = blockIdx.x * 256 + threadIdx.x;
    if (e >= E) return;
    int b = edge[E + e] * RNUM + et[e];
    atomicAdd(&cnt[b], 1u);
}

// pack(edge_count, has_segment) pair-scan, 1024 elems/block.
// Also writes per-block per-relation segment counts (NO global atomics).
__global__ __launch_bounds__(256) void k_scan_part(const u32* cnt, int NB, u64* psum, u32* blockrel) {
    __shared__ u64 red[256];
    __shared__ u32 h20[RNUM];
    int t = threadIdx.x;
    if (t < RNUM) h20[t] = 0;
    __syncthreads();
    int base = blockIdx.x * 1024 + t * 4;
    u64 s = 0;
    for (int i = 0; i < 4; i++) {
        int b = base + i;
        if (b < NB) {
            u32 c = cnt[b];
            s += (u64)c | ((u64)(c > 0) << 32);
            if (c) atomicAdd(&h20[b % RNUM], 1u);   // shared atomic: cheap
        }
    }
    red[t] = s;
    __syncthreads();
    for (int o = 128; o > 0; o >>= 1) {
        if (t < o) red[t] += red[t + o];
        __syncthreads();
    }
    if (t == 0) psum[blockIdx.x] = red[0];
    if (t < RNUM) blockrel[t * BRSTRIDE + blockIdx.x] = h20[t];
}

__global__ __launch_bounds__(256) void k_scan_top(u64* psum, int P, u32* meta,
                                                  u64* escan, int NB, u32* segoff, int N) {
    __shared__ u64 sc[256];
    int t = threadIdx.x;
    u64 loc[8];
    u64 s = 0;
    for (int i = 0; i < 8; i++) {
        int p = t * 8 + i;
        loc[i] = (p < P) ? psum[p] : 0;
        s += loc[i];
    }
    sc[t] = s;
    __syncthreads();
    for (int o = 1; o < 256; o <<= 1) {
        u64 x = (t >= o) ? sc[t - o] : 0;
        __syncthreads();
        sc[t] += x;
        __syncthreads();
    }
    u64 run = sc[t] - s;  // exclusive
    for (int i = 0; i < 8; i++) {
        int p = t * 8 + i;
        if (p < P) { psum[p] = run; run += loc[i]; }
    }
    if (t == 255) {
        u64 tot = sc[255];
        *(u64*)(meta + M_TOT) = tot;
        escan[NB] = tot;
        segoff[N] = (u32)(tot >> 32);
    }
}

__global__ __launch_bounds__(256) void k_scan_add(const u32* cnt, int NB, const u64* psum,
                                                  u64* escan, u32* segoff) {
    __shared__ u64 sc[256];
    int t = threadIdx.x;
    int base = blockIdx.x * 1024 + t * 4;
    u64 v[4];
    u64 s = 0;
    for (int i = 0; i < 4; i++) {
        int b = base + i;
        u32 c = (b < NB) ? cnt[b] : 0;
        v[i] = (u64)c | ((u64)(c > 0) << 32);
        s += v[i];
    }
    sc[t] = s;
    __syncthreads();
    for (int o = 1; o < 256; o <<= 1) {
        u64 x = (t >= o) ? sc[t - o] : 0;
        __syncthreads();
        sc[t] += x;
        __syncthreads();
    }
    u64 run = psum[blockIdx.x] + sc[t] - s;
    for (int i = 0; i < 4; i++) {
        int b = base + i;
        if (b < NB) {
            escan[b] = run;
            if (b % RNUM == 0) segoff[b / RNUM] = (u32)(run >> 32);
            run += v[i];
        }
    }
}

// one block PER RELATION COLUMN: load <=2048 entries, LDS scan, write back exclusive.
__global__ __launch_bounds__(256) void k_colscan2(u32* blockrel, int P, u32* meta) {
    __shared__ u32 sc[256];
    int c = blockIdx.x;
    int t = threadIdx.x;
    u32* col = blockrel + c * BRSTRIDE;
    u32 v[8];
    u32 s = 0;
#pragma unroll
    for (int i = 0; i < 8; i++) {
        int p = t * 8 + i;
        v[i] = (p < P) ? col[p] : 0;
        s += v[i];
    }
    sc[t] = s;
    __syncthreads();
    for (int o = 1; o < 256; o <<= 1) {
        u32 x = (t >= o) ? sc[t - o] : 0;
        __syncthreads();
        sc[t] += x;
        __syncthreads();
    }
    u32 run = sc[t] - s;  // exclusive prefix of this thread's chunk
#pragma unroll
    for (int i = 0; i < 8; i++) {
        int p = t * 8 + i;
        if (p < P) { col[p] = run; run += v[i]; }
    }
    if (t == 255) meta[M_RCNT + c] = sc[255];
}

// tiny: rbase/rtile prefix over 20 relation counts
__global__ void k_rscan(u32* meta) {
    if (threadIdx.x || blockIdx.x) return;
    u32 off = 0, toff = 0;
    for (int r = 0; r < RNUM; r++) {
        meta[M_RBASE + r] = off;
        meta[M_RTILE + r] = toff;
        u32 c = meta[M_RCNT + r];
        off += c;
        toff += (c + 63) >> 6;
    }
    meta[M_RBASE + RNUM] = off;
    meta[M_RTILE + RNUM] = toff;
}

// segment list: segmeta[s] = epos | (cnt<<20); rseg grouped by relation.
// Rank within relation = rbase[r] + blockbase[r] (scanned) + shared-atomic local rank.
__global__ __launch_bounds__(256) void k_build(const u32* cnt, const u64* escan, int NB,
                                               const u32* __restrict__ meta,
                                               const u32* __restrict__ blockrel,
                                               u32* segmeta, u32* rseg) {
    __shared__ u32 h20[RNUM];
    int t = threadIdx.x;
    if (t < RNUM) h20[t] = 0;
    __syncthreads();
    int base = blockIdx.x * 1024 + t * 4;
    for (int i = 0; i < 4; i++) {
        int b = base + i;
        if (b >= NB) break;
        u32 c = cnt[b];
        if (!c) continue;
        int r = b % RNUM;
        u32 my = atomicAdd(&h20[r], 1u);   // shared atomic only
        u64 e = escan[b];
        u32 s = (u32)(e >> 32);
        segmeta[s] = ((u32)e & 0xFFFFFu) | (c << 20);
        rseg[meta[M_RBASE + r] + blockrel[r * BRSTRIDE + blockIdx.x] + my] = s;
    }
}

// counting-sort edge sources into (dst,rel) buckets; consumes cnt as cursor
__global__ void k_scatter2(const int* edge, const int* et, int E,
                           const u64* escan, u32* cnt, int* bsrc2) {
    int e = blockIdx.x * 256 + threadIdx.x;
    if (e >= E) return;
    int b = edge[E + e] * RNUM + et[e];
    u32 old = atomicSub(&cnt[b], 1u);
    u32 pos = (u32)escan[b] + old - 1;
    bsrc2[pos] = edge[e];
}

// ---------------- main passes ----------------

// per 64-segment tile of one relation: gather+mean -> MFMA -> Y[seg] (bf16, no atomics)
// Al: linear [64][128] bf16 + XOR swizzle (byte ^= (row&7)<<4) on both sides.
// B read directly from global (L2-hot), no LDS stage -> 16.6KB LDS, 6 blocks/CU.
__global__ __launch_bounds__(256, 6) void k_agg_gemm(const ushort* __restrict__ h,
                                                     const ushort* __restrict__ wt,
                                                     const int* __restrict__ bsrc2,
                                                     const u32* __restrict__ segmeta,
                                                     const u32* __restrict__ rseg,
                                                     const u32* __restrict__ meta,
                                                     ushort* __restrict__ Y) {
    __shared__ __align__(16) char Al[64 * 256];
    __shared__ int ssid[64];
    int tile = blockIdx.x;
    if (tile >= (int)meta[M_RTILE + RNUM]) return;
    int r = 0;
#pragma unroll
    for (int i = 1; i < RNUM; i++)
        if (tile >= (int)meta[M_RTILE + i]) r = i;
    int j0 = (tile - (int)meta[M_RTILE + r]) * 64;
    int nseg = (int)meta[M_RCNT + r];
    u32 rb = meta[M_RBASE + r];
    int t = threadIdx.x;
    int j = t >> 2, t4 = t & 3;
    // team phase: build mean row j (cols t4*32..+32), write swizzled
    {
        char* arow = Al + j * 256;
        int swz = (j & 7) << 4;
        int sj = j0 + j;
        int s = -1;
        int c = 0, epos = 0;
        if (sj < nseg) {
            s = (int)rseg[rb + sj];
            u32 m = segmeta[s];
            epos = m & 0xFFFFF;
            c = (int)(m >> 20);
        }
        if (t4 == 0) ssid[j] = s;
        if (c == 1) {
            // fast path (86% of segments): straight copy, no f32 round trip
            int src = bsrc2[epos];
            const ushort* hp = h + (size_t)src * DD + t4 * 32;
#pragma unroll
            for (int k = 0; k < 4; k++) {
                s16x8 v = *(const s16x8*)(hp + k * 8);
                *(s16x8*)(arow + ((t4 * 64 + k * 16) ^ swz)) = v;
            }
        } else {
            float a[32];
#pragma unroll
            for (int i = 0; i < 32; i++) a[i] = 0.f;
            for (int q = 0; q < c; q++) {
                int src = bsrc2[epos + q];
                const ushort* hp = h + (size_t)src * DD + t4 * 32;
#pragma unroll
                for (int k = 0; k < 4; k++) {
                    s16x8 v = *(const s16x8*)(hp + k * 8);
#pragma unroll
                    for (int i = 0; i < 8; i++)
                        a[k * 8 + i] += __uint_as_float(((u32)(ushort)v[i]) << 16);
                }
            }
            float inv = (c > 0) ? (1.0f / (float)c) : 0.f;
#pragma unroll
            for (int i = 0; i < 32; i++) a[i] *= inv;
#pragma unroll
            for (int k = 0; k < 4; k++) {
                s16x8 o;
#pragma unroll
                for (int i = 0; i < 8; i++) o[i] = (short)f2bf(a[k * 8 + i]);
                *(s16x8*)(arow + ((t4 * 64 + k * 16) ^ swz)) = o;
            }
        }
    }
    __syncthreads();
    int w = t >> 6, l = t & 63, lr = l & 15, lg = l >> 4;
    const ushort* wr = wt + (size_t)r * DD * DD;
    f32x4 acc[8];
#pragma unroll
    for (int c8 = 0; c8 < 8; c8++) acc[c8] = (f32x4){0.f, 0.f, 0.f, 0.f};
#pragma unroll
    for (int ks = 0; ks < 4; ks++) {
        s16x8 af = *(const s16x8*)(Al + (w * 16 + lr) * 256 + ((ks * 64 + lg * 16) ^ ((lr & 7) << 4)));
#pragma unroll
        for (int c8 = 0; c8 < 8; c8++) {
            s16x8 bf = *(const s16x8*)(wr + (size_t)(c8 * 16 + lr) * DD + ks * 32 + lg * 8);
            acc[c8] = __builtin_amdgcn_mfma_f32_16x16x32_bf16(af, bf, acc[c8], 0, 0, 0);
        }
    }
#pragma unroll
    for (int q = 0; q < 4; q++) {
        int row = w * 16 + lg * 4 + q;
        int s = ssid[row];
        if (s < 0) continue;
        ushort* yp = Y + (size_t)s * DD;
#pragma unroll
        for (int c8 = 0; c8 < 8; c8++) {
            int col = c8 * 16 + lr;
            yp[col] = f2bf(acc[c8][q]);
        }
    }
}

// per 64 nodes: root MFMA + contiguous Y-segment sum + bias (+relu for layer1)
// B (wroot) read direct from global; Al swizzled bf16; Cl fp32 overlays Al after MFMA.
template <int RELU>
__global__ __launch_bounds__(256, 4) void k_out(const ushort* __restrict__ h,
                                                const ushort* __restrict__ wroot,
                                                const float* __restrict__ bias,
                                                const ushort* __restrict__ Y,
                                                const u32* __restrict__ segoff,
                                                ushort* __restrict__ hout,
                                                float* __restrict__ fout, int N) {
    __shared__ __align__(16) char U[64 * 132 * 4];  // Al (first 16KB), then Cl f32
    float* Cl = (float*)U;
    __shared__ float biasl[DD];
    int n0 = blockIdx.x * 64;
    int t = threadIdx.x;
    if (t < DD) biasl[t] = bias[t];
    for (int q = t; q < 1024; q += 256) {
        int row = q >> 4, cb = q & 15;
        int i = n0 + row;
        int4 v = make_int4(0, 0, 0, 0);
        if (i < N) v = *(const int4*)(h + (size_t)i * DD + cb * 8);
        *(int4*)(U + row * 256 + ((cb * 16) ^ ((row & 7) << 4))) = v;
    }
    __syncthreads();
    int w = t >> 6, l = t & 63, lr = l & 15, lg = l >> 4;
    f32x4 acc[8];
#pragma unroll
    for (int c8 = 0; c8 < 8; c8++) acc[c8] = (f32x4){0.f, 0.f, 0.f, 0.f};
#pragma unroll
    for (int ks = 0; ks < 4; ks++) {
        s16x8 af = *(const s16x8*)(U + (w * 16 + lr) * 256 + ((ks * 64 + lg * 16) ^ ((lr & 7) << 4)));
#pragma unroll
        for (int c8 = 0; c8 < 8; c8++) {
            s16x8 bf = *(const s16x8*)(wroot + (size_t)(c8 * 16 + lr) * DD + ks * 32 + lg * 8);
            acc[c8] = __builtin_amdgcn_mfma_f32_16x16x32_bf16(af, bf, acc[c8], 0, 0, 0);
        }
    }
    __syncthreads();  // everyone done reading Al
#pragma unroll
    for (int q = 0; q < 4; q++) {
        int row = w * 16 + lg * 4 + q;
#pragma unroll
        for (int c8 = 0; c8 < 8; c8++) Cl[row * 132 + c8 * 16 + lr] = acc[c8][q];
    }
    __syncthreads();
    int j = t >> 2, t4 = t & 3;
    int node = n0 + j;
    if (node >= N) return;
    float a[32];
#pragma unroll
    for (int k = 0; k < 8; k++) {
        f32x4 cv = *(const f32x4*)(Cl + j * 132 + t4 * 32 + k * 4);
        a[k * 4 + 0] = cv[0]; a[k * 4 + 1] = cv[1]; a[k * 4 + 2] = cv[2]; a[k * 4 + 3] = cv[3];
    }
    u32 s0 = segoff[node], s1 = segoff[node + 1];
    for (u32 s = s0; s < s1; s++) {
        const ushort* yp = Y + (size_t)s * DD + t4 * 32;
#pragma unroll
        for (int k = 0; k < 4; k++) {
            s16x8 v = *(const s16x8*)(yp + k * 8);
#pragma unroll
            for (int i = 0; i < 8; i++)
                a[k * 8 + i] += __uint_as_float(((u32)(ushort)v[i]) << 16);
        }
    }
#pragma unroll
    for (int i = 0; i < 32; i++) a[i] += biasl[t4 * 32 + i];
    if (RELU) {
        ushort* op = hout + (size_t)node * DD + t4 * 32;
#pragma unroll
        for (int k = 0; k < 4; k++) {
            s16x8 o;
#pragma unroll
            for (int i = 0; i < 8; i++) {
                float xv = a[k * 8 + i];
                o[i] = (short)f2bf(xv > 0.f ? xv : 0.f);
            }
            *(s16x8*)(op + k * 8) = o;
        }
    } else {
#pragma unroll
        for (int k = 0; k < 8; k++) {
            f32x4 o = (f32x4){a[k * 4 + 0], a[k * 4 + 1], a[k * 4 + 2], a[k * 4 + 3]};
            *(f32x4*)(fout + (size_t)node * DD + t4 * 32 + k * 4) = o;
        }
    }
}

// ---------------- launch ----------------

extern "C" void kernel_launch(void* const* d_in, const int* in_sizes, int n_in,
                              void* d_out, int out_size, void* d_ws, size_t ws_size,
                              hipStream_t stream) {
    const int* x = (const int*)d_in[0];
    const int* edge = (const int*)d_in[1];
    const int* etype = (const int*)d_in[2];
    const float* emb = (const float*)d_in[3];
    const float* w1 = (const float*)d_in[4];
    const float* root1 = (const float*)d_in[5];
    const float* b1 = (const float*)d_in[6];
    const float* w2 = (const float*)d_in[7];
    const float* root2 = (const float*)d_in[8];
    const float* b2 = (const float*)d_in[9];
    float* out = (float*)d_out;

    const int N = in_sizes[0];
    const int E = in_sizes[2];
    const int NB = N * RNUM;

    char* p = (char*)d_ws;
    auto alloc = [&](size_t bytes) {
        char* q = p;
        p += (bytes + 255) & ~(size_t)255;
        return q;
    };
    int* bsrc2 = (int*)alloc((size_t)E * 4);
    u32* segmeta = (u32*)alloc((size_t)E * 4);
    u32* rseg = (u32*)alloc((size_t)E * 4);
    u32* segoff = (u32*)alloc((size_t)(N + 1) * 4);
    u32* meta = (u32*)alloc(512);
    u32* blockrel = (u32*)alloc((size_t)RNUM * BRSTRIDE * 4);
    ushort* wt1 = (ushort*)alloc((size_t)21 * DD * DD * 2);
    ushort* wt2 = (ushort*)alloc((size_t)21 * DD * DD * 2);
    ushort* hbuf = (ushort*)alloc((size_t)N * DD * 2);
    // scan region, later overlaid by Y (dead by the time Y is written)
    u64* escan = (u64*)alloc((size_t)(NB + 1) * 8);
    u32* cnt = (u32*)alloc((size_t)NB * 4);
    u64* psum = (u64*)alloc(2048 * 8);
    ushort* Y = (ushort*)escan;
    {   // extend carve so Y's worst-case footprint is reserved
        char* yend = (char*)escan + (size_t)E * DD * 2;
        if (yend > p) p = yend;
    }

    hipMemsetAsync(cnt, 0, (size_t)NB * 4, stream);
    hipMemsetAsync(meta, 0, 512, stream);

    int blkE = (E + 255) / 256;
    int blkH = (N * 32 + 255) / 256;
    int P = (NB + 1023) / 1024;
    int TILES = (E + 63) / 64 + RNUM;
    int blkOut = (N + 63) / 64;

    k_transpose<<<42, 256, 0, stream>>>(w1, root1, w2, root2, wt1, wt2);
    k_gather_h<<<blkH, 256, 0, stream>>>(x, emb, hbuf, N);
    k_hist<<<blkE, 256, 0, stream>>>(edge, etype, E, cnt);
    k_scan_part<<<P, 256, 0, stream>>>(cnt, NB, psum, blockrel);
    k_scan_top<<<1, 256, 0, stream>>>(psum, P, meta, escan, NB, segoff, N);
    k_scan_add<<<P, 256, 0, stream>>>(cnt, NB, psum, escan, segoff);
    k_colscan2<<<RNUM, 256, 0, stream>>>(blockrel, P, meta);
    k_rscan<<<1, 64, 0, stream>>>(meta);
    k_build<<<P, 256, 0, stream>>>(cnt, escan, NB, meta, blockrel, segmeta, rseg);
    k_scatter2<<<blkE, 256, 0, stream>>>(edge, etype, E, escan, cnt, bsrc2);

    // layer 1 (k_out writes relu'd bf16 back into hbuf in place)
    k_agg_gemm<<<TILES, 256, 0, stream>>>(hbuf, wt1, bsrc2, segmeta, rseg, meta, Y);
    k_out<1><<<blkOut, 256, 0, stream>>>(hbuf, wt1 + 20 * DD * DD, b1, Y, segoff, hbuf, nullptr, N);

    // layer 2
    k_agg_gemm<<<TILES, 256, 0, stream>>>(hbuf, wt2, bsrc2, segmeta, rseg, meta, Y);
    k_out<0><<<blkOut, 256, 0, stream>>>(hbuf, wt2 + 20 * DD * DD, b2, Y, segoff, nullptr, out, N);
}

// Round 9
// 466.810 us; speedup vs baseline: 1.3952x; 1.3952x over previous
//
#include <hip/hip_runtime.h>

#define DD 128
#define RNUM 20

typedef __attribute__((ext_vector_type(4))) float f32x4;
typedef __attribute__((ext_vector_type(8))) short s16x8;
typedef unsigned long long u64;
typedef unsigned int u32;

__device__ inline ushort f2bf(float f) {
    unsigned u = __float_as_uint(f);
    unsigned r = (u + 0x7FFF + ((u >> 16) & 1)) >> 16;  // RNE
    return (ushort)r;
}

// meta layout (u32): [0..19] rcnt; [20..40] rbase; [41..61] rtileoff; u64 totals @ 88
#define M_RCNT 0
#define M_RBASE 20
#define M_RTILE 41
#define M_TOT 88
#define BRSTRIDE 2048

// ---------------- weight prep / embedding gather ----------------

__global__ void k_transpose(const float* w1, const float* root1,
                            const float* w2, const float* root2,
                            ushort* wt1, ushort* wt2) {
    int m = blockIdx.x;  // 0..41
    const float* src;
    ushort* dst;
    if (m < 21) { src = (m == 20) ? root1 : w1 + m * DD * DD; dst = wt1 + m * DD * DD; }
    else { int mm = m - 21; src = (mm == 20) ? root2 : w2 + mm * DD * DD; dst = wt2 + mm * DD * DD; }
    for (int idx = threadIdx.x; idx < DD * DD; idx += blockDim.x) {
        int n = idx >> 7, k = idx & 127;
        dst[idx] = f2bf(src[k * DD + n]);   // wt[n][k] = w[k][n]
    }
}

__global__ void k_gather_h(const int* x, const float* emb, ushort* h, int N) {
    int id = blockIdx.x * blockDim.x + threadIdx.x;  // one thread per 4 elems
    if (id >= N * 32) return;
    int n = id >> 5, c = (id & 31) * 4;
    int xn = x[n];
    float4 v = *(const float4*)(emb + (size_t)xn * DD + c);
    ushort4 o;
    o.x = f2bf(v.x); o.y = f2bf(v.y); o.z = f2bf(v.z); o.w = f2bf(v.w);
    *(ushort4*)(h + (size_t)n * DD + c) = o;
}

// ---------------- sort-by-(dst,rel) preprocessing ----------------

__global__ void k_hist(const int* edge, const int* et, int E, u32* cnt) {
    int e = blockIdx.x * 256 + threadIdx.x;
    if (e >= E) return;
    int b = edge[E + e] * RNUM + et[e];
    atomicAdd(&cnt[b], 1u);
}

// pack(edge_count, has_segment) pair-scan, 1024 elems/block.
// Also writes per-block per-relation segment counts (NO global atomics).
__global__ __launch_bounds__(256) void k_scan_part(const u32* cnt, int NB, u64* psum, u32* blockrel) {
    __shared__ u64 red[256];
    __shared__ u32 h20[RNUM];
    int t = threadIdx.x;
    if (t < RNUM) h20[t] = 0;
    __syncthreads();
    int base = blockIdx.x * 1024 + t * 4;
    u64 s = 0;
    for (int i = 0; i < 4; i++) {
        int b = base + i;
        if (b < NB) {
            u32 c = cnt[b];
            s += (u64)c | ((u64)(c > 0) << 32);
            if (c) atomicAdd(&h20[b % RNUM], 1u);   // shared atomic: cheap
        }
    }
    red[t] = s;
    __syncthreads();
    for (int o = 128; o > 0; o >>= 1) {
        if (t < o) red[t] += red[t + o];
        __syncthreads();
    }
    if (t == 0) psum[blockIdx.x] = red[0];
    if (t < RNUM) blockrel[t * BRSTRIDE + blockIdx.x] = h20[t];
}

__global__ __launch_bounds__(256) void k_scan_top(u64* psum, int P, u32* meta,
                                                  u64* escan, int NB, u32* segoff, int N) {
    __shared__ u64 sc[256];
    int t = threadIdx.x;
    u64 loc[8];
    u64 s = 0;
    for (int i = 0; i < 8; i++) {
        int p = t * 8 + i;
        loc[i] = (p < P) ? psum[p] : 0;
        s += loc[i];
    }
    sc[t] = s;
    __syncthreads();
    for (int o = 1; o < 256; o <<= 1) {
        u64 x = (t >= o) ? sc[t - o] : 0;
        __syncthreads();
        sc[t] += x;
        __syncthreads();
    }
    u64 run = sc[t] - s;  // exclusive
    for (int i = 0; i < 8; i++) {
        int p = t * 8 + i;
        if (p < P) { psum[p] = run; run += loc[i]; }
    }
    if (t == 255) {
        u64 tot = sc[255];
        *(u64*)(meta + M_TOT) = tot;
        escan[NB] = tot;
        segoff[N] = (u32)(tot >> 32);
    }
}

__global__ __launch_bounds__(256) void k_scan_add(const u32* cnt, int NB, const u64* psum,
                                                  u64* escan, u32* segoff) {
    __shared__ u64 sc[256];
    int t = threadIdx.x;
    int base = blockIdx.x * 1024 + t * 4;
    u64 v[4];
    u64 s = 0;
    for (int i = 0; i < 4; i++) {
        int b = base + i;
        u32 c = (b < NB) ? cnt[b] : 0;
        v[i] = (u64)c | ((u64)(c > 0) << 32);
        s += v[i];
    }
    sc[t] = s;
    __syncthreads();
    for (int o = 1; o < 256; o <<= 1) {
        u64 x = (t >= o) ? sc[t - o] : 0;
        __syncthreads();
        sc[t] += x;
        __syncthreads();
    }
    u64 run = psum[blockIdx.x] + sc[t] - s;
    for (int i = 0; i < 4; i++) {
        int b = base + i;
        if (b < NB) {
            escan[b] = run;
            if (b % RNUM == 0) segoff[b / RNUM] = (u32)(run >> 32);
            run += v[i];
        }
    }
}

// one block PER RELATION COLUMN: load <=2048 entries, LDS scan, write back exclusive.
__global__ __launch_bounds__(256) void k_colscan2(u32* blockrel, int P, u32* meta) {
    __shared__ u32 sc[256];
    int c = blockIdx.x;
    int t = threadIdx.x;
    u32* col = blockrel + c * BRSTRIDE;
    u32 v[8];
    u32 s = 0;
#pragma unroll
    for (int i = 0; i < 8; i++) {
        int p = t * 8 + i;
        v[i] = (p < P) ? col[p] : 0;
        s += v[i];
    }
    sc[t] = s;
    __syncthreads();
    for (int o = 1; o < 256; o <<= 1) {
        u32 x = (t >= o) ? sc[t - o] : 0;
        __syncthreads();
        sc[t] += x;
        __syncthreads();
    }
    u32 run = sc[t] - s;  // exclusive prefix of this thread's chunk
#pragma unroll
    for (int i = 0; i < 8; i++) {
        int p = t * 8 + i;
        if (p < P) { col[p] = run; run += v[i]; }
    }
    if (t == 255) meta[M_RCNT + c] = sc[255];
}

// tiny: rbase/rtile prefix over 20 relation counts
__global__ void k_rscan(u32* meta) {
    if (threadIdx.x || blockIdx.x) return;
    u32 off = 0, toff = 0;
    for (int r = 0; r < RNUM; r++) {
        meta[M_RBASE + r] = off;
        meta[M_RTILE + r] = toff;
        u32 c = meta[M_RCNT + r];
        off += c;
        toff += (c + 63) >> 6;
    }
    meta[M_RBASE + RNUM] = off;
    meta[M_RTILE + RNUM] = toff;
}

// segment list: segmeta[s] = epos | (cnt<<20); rseg grouped by relation.
// Rank within relation = rbase[r] + blockbase[r] (scanned) + shared-atomic local rank.
__global__ __launch_bounds__(256) void k_build(const u32* cnt, const u64* escan, int NB,
                                               const u32* __restrict__ meta,
                                               const u32* __restrict__ blockrel,
                                               u32* segmeta, u32* rseg) {
    __shared__ u32 h20[RNUM];
    int t = threadIdx.x;
    if (t < RNUM) h20[t] = 0;
    __syncthreads();
    int base = blockIdx.x * 1024 + t * 4;
    for (int i = 0; i < 4; i++) {
        int b = base + i;
        if (b >= NB) break;
        u32 c = cnt[b];
        if (!c) continue;
        int r = b % RNUM;
        u32 my = atomicAdd(&h20[r], 1u);   // shared atomic only
        u64 e = escan[b];
        u32 s = (u32)(e >> 32);
        segmeta[s] = ((u32)e & 0xFFFFFu) | (c << 20);
        rseg[meta[M_RBASE + r] + blockrel[r * BRSTRIDE + blockIdx.x] + my] = s;
    }
}

// counting-sort edge sources into (dst,rel) buckets; consumes cnt as cursor
__global__ void k_scatter2(const int* edge, const int* et, int E,
                           const u64* escan, u32* cnt, int* bsrc2) {
    int e = blockIdx.x * 256 + threadIdx.x;
    if (e >= E) return;
    int b = edge[E + e] * RNUM + et[e];
    u32 old = atomicSub(&cnt[b], 1u);
    u32 pos = (u32)escan[b] + old - 1;
    bsrc2[pos] = edge[e];
}

// ---------------- main passes ----------------

// per 64-segment tile of one relation: gather+mean -> MFMA -> Y[seg] (bf16, no atomics).
// Al: linear [64][128] bf16 + XOR swizzle on both sides. B: per-wave column split
// (wave w owns cols [32w,32w+32)) -> 8 s16x8 fragments loaded ONCE into registers,
// issued before the barrier so L2 latency hides under the slowest gather wave.
__global__ __launch_bounds__(256, 4) void k_agg_gemm(const ushort* __restrict__ h,
                                                     const ushort* __restrict__ wt,
                                                     const int* __restrict__ bsrc2,
                                                     const u32* __restrict__ segmeta,
                                                     const u32* __restrict__ rseg,
                                                     const u32* __restrict__ meta,
                                                     ushort* __restrict__ Y) {
    __shared__ __align__(16) char Al[64 * 256];
    __shared__ int ssid[64];
    int tile = blockIdx.x;
    if (tile >= (int)meta[M_RTILE + RNUM]) return;
    int r = 0;
#pragma unroll
    for (int i = 1; i < RNUM; i++)
        if (tile >= (int)meta[M_RTILE + i]) r = i;
    int j0 = (tile - (int)meta[M_RTILE + r]) * 64;
    int nseg = (int)meta[M_RCNT + r];
    u32 rb = meta[M_RBASE + r];
    int t = threadIdx.x;
    int j = t >> 2, t4 = t & 3;
    // team phase: build mean row j (cols t4*32..+32), write swizzled
    {
        char* arow = Al + j * 256;
        int swz = (j & 7) << 4;
        int sj = j0 + j;
        int s = -1;
        int c = 0, epos = 0;
        if (sj < nseg) {
            s = (int)rseg[rb + sj];
            u32 m = segmeta[s];
            epos = m & 0xFFFFF;
            c = (int)(m >> 20);
        }
        if (t4 == 0) ssid[j] = s;
        if (c == 1) {
            // fast path (~86% of segments): straight copy, no f32 round trip
            int src = bsrc2[epos];
            const ushort* hp = h + (size_t)src * DD + t4 * 32;
#pragma unroll
            for (int k = 0; k < 4; k++) {
                s16x8 v = *(const s16x8*)(hp + k * 8);
                *(s16x8*)(arow + ((t4 * 64 + k * 16) ^ swz)) = v;
            }
        } else {
            float a[32];
#pragma unroll
            for (int i = 0; i < 32; i++) a[i] = 0.f;
            for (int q = 0; q < c; q++) {
                int src = bsrc2[epos + q];
                const ushort* hp = h + (size_t)src * DD + t4 * 32;
#pragma unroll
                for (int k = 0; k < 4; k++) {
                    s16x8 v = *(const s16x8*)(hp + k * 8);
#pragma unroll
                    for (int i = 0; i < 8; i++)
                        a[k * 8 + i] += __uint_as_float(((u32)(ushort)v[i]) << 16);
                }
            }
            float inv = (c > 0) ? (1.0f / (float)c) : 0.f;
#pragma unroll
            for (int i = 0; i < 32; i++) a[i] *= inv;
#pragma unroll
            for (int k = 0; k < 4; k++) {
                s16x8 o;
#pragma unroll
                for (int i = 0; i < 8; i++) o[i] = (short)f2bf(a[k * 8 + i]);
                *(s16x8*)(arow + ((t4 * 64 + k * 16) ^ swz)) = o;
            }
        }
    }
    // per-wave B fragments (cols w*32..w*32+32), loaded once; latency hides under barrier
    int w = t >> 6, l = t & 63, lr = l & 15, lg = l >> 4;
    const ushort* wr = wt + (size_t)r * DD * DD;
    s16x8 bq[2][4];
#pragma unroll
    for (int cc = 0; cc < 2; cc++)
#pragma unroll
        for (int ks = 0; ks < 4; ks++)
            bq[cc][ks] = *(const s16x8*)(wr + (size_t)(w * 32 + cc * 16 + lr) * DD + ks * 32 + lg * 8);
    __syncthreads();
    f32x4 acc[4][2];
#pragma unroll
    for (int rt = 0; rt < 4; rt++)
#pragma unroll
        for (int cc = 0; cc < 2; cc++) acc[rt][cc] = (f32x4){0.f, 0.f, 0.f, 0.f};
#pragma unroll
    for (int ks = 0; ks < 4; ks++) {
#pragma unroll
        for (int rt = 0; rt < 4; rt++) {
            s16x8 af = *(const s16x8*)(Al + (rt * 16 + lr) * 256 + ((ks * 64 + lg * 16) ^ ((lr & 7) << 4)));
#pragma unroll
            for (int cc = 0; cc < 2; cc++)
                acc[rt][cc] = __builtin_amdgcn_mfma_f32_16x16x32_bf16(af, bq[cc][ks], acc[rt][cc], 0, 0, 0);
        }
    }
#pragma unroll
    for (int rt = 0; rt < 4; rt++) {
#pragma unroll
        for (int q = 0; q < 4; q++) {
            int row = rt * 16 + lg * 4 + q;
            int s = ssid[row];
            if (s < 0) continue;
            ushort* yp = Y + (size_t)s * DD + w * 32;
#pragma unroll
            for (int cc = 0; cc < 2; cc++)
                yp[cc * 16 + lr] = f2bf(acc[rt][cc][q]);
        }
    }
}

// per 64 nodes: root MFMA + contiguous Y-segment sum + bias (+relu for layer1)
// Same per-wave column-split B-in-registers; Al swizzled bf16; Cl fp32 overlays Al.
template <int RELU>
__global__ __launch_bounds__(256, 4) void k_out(const ushort* __restrict__ h,
                                                const ushort* __restrict__ wroot,
                                                const float* __restrict__ bias,
                                                const ushort* __restrict__ Y,
                                                const u32* __restrict__ segoff,
                                                ushort* __restrict__ hout,
                                                float* __restrict__ fout, int N) {
    __shared__ __align__(16) char U[64 * 132 * 4];  // Al (first 16KB), then Cl f32
    float* Cl = (float*)U;
    __shared__ float biasl[DD];
    int n0 = blockIdx.x * 64;
    int t = threadIdx.x;
    if (t < DD) biasl[t] = bias[t];
    for (int q = t; q < 1024; q += 256) {
        int row = q >> 4, cb = q & 15;
        int i = n0 + row;
        int4 v = make_int4(0, 0, 0, 0);
        if (i < N) v = *(const int4*)(h + (size_t)i * DD + cb * 8);
        *(int4*)(U + row * 256 + ((cb * 16) ^ ((row & 7) << 4))) = v;
    }
    int w = t >> 6, l = t & 63, lr = l & 15, lg = l >> 4;
    s16x8 bq[2][4];
#pragma unroll
    for (int cc = 0; cc < 2; cc++)
#pragma unroll
        for (int ks = 0; ks < 4; ks++)
            bq[cc][ks] = *(const s16x8*)(wroot + (size_t)(w * 32 + cc * 16 + lr) * DD + ks * 32 + lg * 8);
    __syncthreads();
    f32x4 acc[4][2];
#pragma unroll
    for (int rt = 0; rt < 4; rt++)
#pragma unroll
        for (int cc = 0; cc < 2; cc++) acc[rt][cc] = (f32x4){0.f, 0.f, 0.f, 0.f};
#pragma unroll
    for (int ks = 0; ks < 4; ks++) {
#pragma unroll
        for (int rt = 0; rt < 4; rt++) {
            s16x8 af = *(const s16x8*)(U + (rt * 16 + lr) * 256 + ((ks * 64 + lg * 16) ^ ((lr & 7) << 4)));
#pragma unroll
            for (int cc = 0; cc < 2; cc++)
                acc[rt][cc] = __builtin_amdgcn_mfma_f32_16x16x32_bf16(af, bq[cc][ks], acc[rt][cc], 0, 0, 0);
        }
    }
    __syncthreads();  // everyone done reading Al
#pragma unroll
    for (int rt = 0; rt < 4; rt++) {
#pragma unroll
        for (int q = 0; q < 4; q++) {
            int row = rt * 16 + lg * 4 + q;
#pragma unroll
            for (int cc = 0; cc < 2; cc++)
                Cl[row * 132 + w * 32 + cc * 16 + lr] = acc[rt][cc][q];
        }
    }
    __syncthreads();
    int j = t >> 2, t4 = t & 3;
    int node = n0 + j;
    if (node >= N) return;
    float a[32];
#pragma unroll
    for (int k = 0; k < 8; k++) {
        f32x4 cv = *(const f32x4*)(Cl + j * 132 + t4 * 32 + k * 4);
        a[k * 4 + 0] = cv[0]; a[k * 4 + 1] = cv[1]; a[k * 4 + 2] = cv[2]; a[k * 4 + 3] = cv[3];
    }
    u32 s0 = segoff[node], s1 = segoff[node + 1];
    for (u32 s = s0; s < s1; s++) {
        const ushort* yp = Y + (size_t)s * DD + t4 * 32;
#pragma unroll
        for (int k = 0; k < 4; k++) {
            s16x8 v = *(const s16x8*)(yp + k * 8);
#pragma unroll
            for (int i = 0; i < 8; i++)
                a[k * 8 + i] += __uint_as_float(((u32)(ushort)v[i]) << 16);
        }
    }
#pragma unroll
    for (int i = 0; i < 32; i++) a[i] += biasl[t4 * 32 + i];
    if (RELU) {
        ushort* op = hout + (size_t)node * DD + t4 * 32;
#pragma unroll
        for (int k = 0; k < 4; k++) {
            s16x8 o;
#pragma unroll
            for (int i = 0; i < 8; i++) {
                float xv = a[k * 8 + i];
                o[i] = (short)f2bf(xv > 0.f ? xv : 0.f);
            }
            *(s16x8*)(op + k * 8) = o;
        }
    } else {
#pragma unroll
        for (int k = 0; k < 8; k++) {
            f32x4 o = (f32x4){a[k * 4 + 0], a[k * 4 + 1], a[k * 4 + 2], a[k * 4 + 3]};
            *(f32x4*)(fout + (size_t)node * DD + t4 * 32 + k * 4) = o;
        }
    }
}

// ---------------- launch ----------------

extern "C" void kernel_launch(void* const* d_in, const int* in_sizes, int n_in,
                              void* d_out, int out_size, void* d_ws, size_t ws_size,
                              hipStream_t stream) {
    const int* x = (const int*)d_in[0];
    const int* edge = (const int*)d_in[1];
    const int* etype = (const int*)d_in[2];
    const float* emb = (const float*)d_in[3];
    const float* w1 = (const float*)d_in[4];
    const float* root1 = (const float*)d_in[5];
    const float* b1 = (const float*)d_in[6];
    const float* w2 = (const float*)d_in[7];
    const float* root2 = (const float*)d_in[8];
    const float* b2 = (const float*)d_in[9];
    float* out = (float*)d_out;

    const int N = in_sizes[0];
    const int E = in_sizes[2];
    const int NB = N * RNUM;

    char* p = (char*)d_ws;
    auto alloc = [&](size_t bytes) {
        char* q = p;
        p += (bytes + 255) & ~(size_t)255;
        return q;
    };
    int* bsrc2 = (int*)alloc((size_t)E * 4);
    u32* segmeta = (u32*)alloc((size_t)E * 4);
    u32* rseg = (u32*)alloc((size_t)E * 4);
    u32* segoff = (u32*)alloc((size_t)(N + 1) * 4);
    u32* meta = (u32*)alloc(512);
    u32* blockrel = (u32*)alloc((size_t)RNUM * BRSTRIDE * 4);
    ushort* wt1 = (ushort*)alloc((size_t)21 * DD * DD * 2);
    ushort* wt2 = (ushort*)alloc((size_t)21 * DD * DD * 2);
    ushort* hbuf = (ushort*)alloc((size_t)N * DD * 2);
    // scan region, later overlaid by Y (dead by the time Y is written)
    u64* escan = (u64*)alloc((size_t)(NB + 1) * 8);
    u32* cnt = (u32*)alloc((size_t)NB * 4);
    u64* psum = (u64*)alloc(2048 * 8);
    ushort* Y = (ushort*)escan;
    {   // extend carve so Y's worst-case footprint is reserved
        char* yend = (char*)escan + (size_t)E * DD * 2;
        if (yend > p) p = yend;
    }

    hipMemsetAsync(cnt, 0, (size_t)NB * 4, stream);
    hipMemsetAsync(meta, 0, 512, stream);

    int blkE = (E + 255) / 256;
    int blkH = (N * 32 + 255) / 256;
    int P = (NB + 1023) / 1024;
    int TILES = (E + 63) / 64 + RNUM;
    int blkOut = (N + 63) / 64;

    k_transpose<<<42, 256, 0, stream>>>(w1, root1, w2, root2, wt1, wt2);
    k_gather_h<<<blkH, 256, 0, stream>>>(x, emb, hbuf, N);
    k_hist<<<blkE, 256, 0, stream>>>(edge, etype, E, cnt);
    k_scan_part<<<P, 256, 0, stream>>>(cnt, NB, psum, blockrel);
    k_scan_top<<<1, 256, 0, stream>>>(psum, P, meta, escan, NB, segoff, N);
    k_scan_add<<<P, 256, 0, stream>>>(cnt, NB, psum, escan, segoff);
    k_colscan2<<<RNUM, 256, 0, stream>>>(blockrel, P, meta);
    k_rscan<<<1, 64, 0, stream>>>(meta);
    k_build<<<P, 256, 0, stream>>>(cnt, escan, NB, meta, blockrel, segmeta, rseg);
    k_scatter2<<<blkE, 256, 0, stream>>>(edge, etype, E, escan, cnt, bsrc2);

    // layer 1 (k_out writes relu'd bf16 back into hbuf in place)
    k_agg_gemm<<<TILES, 256, 0, stream>>>(hbuf, wt1, bsrc2, segmeta, rseg, meta, Y);
    k_out<1><<<blkOut, 256, 0, stream>>>(hbuf, wt1 + 20 * DD * DD, b1, Y, segoff, hbuf, nullptr, N);

    // layer 2
    k_agg_gemm<<<TILES, 256, 0, stream>>>(hbuf, wt2, bsrc2, segmeta, rseg, meta, Y);
    k_out<0><<<blkOut, 256, 0, stream>>>(hbuf, wt2 + 20 * DD * DD, b2, Y, segoff, nullptr, out, N);
}